// Round 3
// baseline (272.424 us; speedup 1.0000x reference)
//
#include <hip/hip_runtime.h>

// out[b][w][f][c] = x[b][w+f][c],  B=128, L=4096, F=32, C=4, fp32.
// C=4 floats = one 16B vector per (b,w,f).
// Tile: one block = one batch b x one 32-window chunk.
//   4065 windows = 127 full chunks of 32 + 1 chunk with a single window.
//   grid = 128 batches * 128 chunks = 16384 blocks, 256 threads.
// Per block: write 32*32 = 1024 vec4 (16 KB), read span of 63 vec4 (1 KB,
// reused 32x from L1). All index math is shift/mask - no integer division.
// Stores are nontemporal (write-once stream) to keep x resident in L2.

using f32x4 = __attribute__((ext_vector_type(4))) float;  // native vector: nt-store OK

constexpr int F      = 32;
constexpr int L      = 4096;
constexpr int NW     = L - F + 1;   // 4065
constexpr int NCHUNK = 128;         // ceil(4065/32)

__global__ __launch_bounds__(256) void im2col_tile(const f32x4* __restrict__ x,
                                                   f32x4* __restrict__ out) {
    const int chunk = blockIdx.x & (NCHUNK - 1);
    const int b     = blockIdx.x >> 7;          // / NCHUNK
    const int w0    = chunk << 5;               // * 32 windows
    const int t     = threadIdx.x;

    const f32x4* __restrict__ xb = x + (long long)b * L;
    f32x4* __restrict__ ob       = out + ((long long)b * NW + w0) * F;

    // Each thread: 4 output vec4s at ol = t + k*256 (coalesced per k).
    // f = ol & 31, wloc = ol >> 5. Batch loads (ILP=4), then stores.
    f32x4 v[4];
    bool  ok[4];

    #pragma unroll
    for (int k = 0; k < 4; ++k) {
        const int ol   = t + k * 256;
        const int wloc = ol >> 5;
        const int f    = ol & (F - 1);
        ok[k] = (w0 + wloc) < NW;
        if (ok[k]) v[k] = xb[w0 + wloc + f];    // max index 4064+31 = 4095
    }

    #pragma unroll
    for (int k = 0; k < 4; ++k) {
        const int ol = t + k * 256;
        if (ok[k]) __builtin_nontemporal_store(v[k], &ob[ol]);
    }
}

extern "C" void kernel_launch(void* const* d_in, const int* in_sizes, int n_in,
                              void* d_out, int out_size, void* d_ws, size_t ws_size,
                              hipStream_t stream) {
    const f32x4* x = (const f32x4*)d_in[0];
    f32x4* out     = (f32x4*)d_out;

    const int grid = 128 * NCHUNK;   // B * chunks = 16384
    im2col_tile<<<grid, 256, 0, stream>>>(x, out);
}